// Round 5
// baseline (309.118 us; speedup 1.0000x reference)
//
#include <hip/hip_runtime.h>
#include <cstdint>
#include <cstddef>

// Shapes (fixed): B=1024, N=2, HIST=64, D=256, E=128, NH=8, HD=32, s=128
// queries kept: s=63 (q=0), s=127 (q=1)

typedef short bf16x8 __attribute__((ext_vector_type(8)));
typedef float f32x4 __attribute__((ext_vector_type(4)));

#define MFMA16(A, B, C) __builtin_amdgcn_mfma_f32_16x16x32_bf16((A), (B), (C), 0, 0, 0)

static __device__ __forceinline__ uint16_t f2bf(float f) {
    uint32_t u = __builtin_bit_cast(uint32_t, f);
    u += 0x7FFFu + ((u >> 16) & 1u);
    return (uint16_t)(u >> 16);
}
static __device__ __forceinline__ uint32_t pack2(float a, float b) {
    return (uint32_t)f2bf(a) | ((uint32_t)f2bf(b) << 16);
}

// ---------------------------------------------------------------------------
// K0: z<3: transpose Wq/Wv/Wo (fp32 [k][n]) -> bf16 [n][264]
//     z==3: straight-convert Wk -> bf16 [j][264].  64 blocks, ~4 us.
// ---------------------------------------------------------------------------
__global__ __launch_bounds__(256) void k_wt(
    const float* __restrict__ Wq, const float* __restrict__ Wv,
    const float* __restrict__ Wo, const float* __restrict__ Wk,
    uint16_t* __restrict__ WqT, uint16_t* __restrict__ WvT,
    uint16_t* __restrict__ WoT, uint16_t* __restrict__ WkB)
{
    const int t = threadIdx.x;
    const int tr = blockIdx.x, tc = blockIdx.y, z = blockIdx.z;
    if (z == 3) {
        #pragma unroll
        for (int i = 0; i < 16; i++) {
            int flat = i * 256 + t;
            int lr = flat >> 6, lc = flat & 63;
            WkB[(size_t)(tr * 64 + lr) * 264 + tc * 64 + lc] =
                f2bf(Wk[(size_t)(tr * 64 + lr) * 256 + tc * 64 + lc]);
        }
        return;
    }
    const float* W = (z == 0) ? Wq : ((z == 1) ? Wv : Wo);
    uint16_t* O = (z == 0) ? WqT : ((z == 1) ? WvT : WoT);
    __shared__ float tile[64][65];
    #pragma unroll
    for (int i = 0; i < 16; i++) {
        int flat = i * 256 + t;
        int lr = flat >> 6, lc = flat & 63;
        tile[lr][lc] = W[(size_t)(tr * 64 + lr) * 256 + tc * 64 + lc];
    }
    __syncthreads();
    #pragma unroll
    for (int i = 0; i < 16; i++) {
        int flat = i * 256 + t;
        int orow = flat >> 6, oc = flat & 63;
        O[(size_t)(tc * 64 + orow) * 264 + tr * 64 + oc] = f2bf(tile[oc][orow]);
    }
}

// ---------------------------------------------------------------------------
// K1 (merged, parallel roles): blocks [0,256): edge modulations (4 batches);
// blocks [256,512): Q/U computation (4 batches each).
// ---------------------------------------------------------------------------
__global__ __launch_bounds__(256) void k_eq(
    const float* __restrict__ edge,
    const float* __restrict__ Wgate, const float* __restrict__ bgate,
    const float* __restrict__ Wscale, const float* __restrict__ bscale,
    const float* __restrict__ Wshift, const float* __restrict__ bshift,
    const float* __restrict__ Wbias, const float* __restrict__ bbias,
    const float* __restrict__ Whead, const float* __restrict__ bhead,
    float* __restrict__ sp, float* __restrict__ tp, float* __restrict__ ebhs,
    const float* __restrict__ node, const uint16_t* __restrict__ WqT,
    const uint16_t* __restrict__ WkB, const float* __restrict__ bq,
    uint16_t* __restrict__ U)
{
    __shared__ char smem[2 * 16 * 264 * 2]; // 16.9 KB, both roles fit
    const int t = threadIdx.x;
    if (blockIdx.x < 256) {
        // ---- edge path ----
        float* eL = (float*)smem; // [4][128]
        const int b0 = blockIdx.x * 4;
        for (int idx = t; idx < 512; idx += 256) {
            int bi = idx >> 7, e = idx & 127;
            eL[bi * 128 + e] = edge[(size_t)(b0 + bi) * 128 + e];
        }
        __syncthreads();
        float ag[4] = {0, 0, 0, 0}, asr[4] = {0, 0, 0, 0}, ah[4] = {0, 0, 0, 0};
        for (int e = 0; e < 128; e++) {
            float wg = Wgate[e * 256 + t];
            float wsc = Wscale[e * 256 + t];
            float wsh = Wshift[e * 256 + t];
            #pragma unroll
            for (int bi = 0; bi < 4; bi++) {
                float xv = eL[bi * 128 + e];
                ag[bi] = fmaf(xv, wg, ag[bi]);
                asr[bi] = fmaf(xv, wsc, asr[bi]);
                ah[bi] = fmaf(xv, wsh, ah[bi]);
            }
        }
        float bg = bgate[t], bs = bscale[t], bsh = bshift[t];
        #pragma unroll
        for (int bi = 0; bi < 4; bi++) {
            float g = 1.0f / (1.0f + __expf(-(ag[bi] + bg)));
            float sc = tanhf(asr[bi] + bs);
            float sh = ah[bi] + bsh;
            sp[(size_t)(b0 + bi) * 256 + t] = (1.0f + sc) * g;
            tp[(size_t)(b0 + bi) * 256 + t] = sh * g;
        }
        if (t < 64) {
            int bi = t >> 4, o = t & 15, h = o & 7;
            const float* W = (o < 8) ? Wbias : Whead;
            float a = 0.0f;
            for (int e = 0; e < 128; e++) a = fmaf(eL[bi * 128 + e], W[e * 8 + h], a);
            float val = (o < 8) ? (a + bbias[h]) : tanhf(a + bhead[h]);
            ebhs[(size_t)(b0 + bi) * 16 + o] = val;
        }
        return;
    }
    // ---- qu path: Q = x_q @ Wq + bq; U[j][(b,q,h)] = sum_d Wk[j,d] Q[q,d] ----
    uint16_t* xq = (uint16_t*)smem;                 // [16][264]
    uint16_t* QL = (uint16_t*)smem + 16 * 264;      // [16][264]
    const int lane = t & 63, w = t >> 6, c = lane & 15, quad = lane >> 4;
    const int b0 = (blockIdx.x - 256) * 4;
    #pragma unroll
    for (int i = 0; i < 4; i++) {
        int flat4 = i * 256 + t;
        int row = flat4 >> 6, c4 = flat4 & 63;
        int r = row & 7;
        int bb = b0 + (r >> 1);
        int s = (r & 1) ? 127 : 63;
        const float4 v = *(const float4*)(node + ((size_t)(bb * 128 + s)) * 256 + c4 * 4);
        uint2 pv; pv.x = pack2(v.x, v.y); pv.y = pack2(v.z, v.w);
        *(uint2*)&xq[row * 264 + c4 * 4] = pv;
    }
    __syncthreads();
    f32x4 zero = {0, 0, 0, 0};
    f32x4 acc[4];
    #pragma unroll
    for (int i = 0; i < 4; i++) acc[i] = zero;
    #pragma unroll
    for (int kk = 0; kk < 8; kk++) {
        bf16x8 afr = *(const bf16x8*)&xq[c * 264 + kk * 32 + quad * 8];
        #pragma unroll
        for (int i = 0; i < 4; i++) {
            int nt = w * 4 + i;
            bf16x8 bfr = *(const bf16x8*)&WqT[(size_t)(nt * 16 + c) * 264 + kk * 32 + quad * 8];
            acc[i] = MFMA16(afr, bfr, acc[i]);
        }
    }
    #pragma unroll
    for (int i = 0; i < 4; i++) {
        int nt = w * 4 + i;
        float bqv = bq[nt * 16 + c];
        #pragma unroll
        for (int r = 0; r < 4; r++) {
            QL[(quad * 4 + r) * 264 + nt * 16 + c] = f2bf(acc[i][r] + bqv);
        }
    }
    __syncthreads();
    for (int hh = 0; hh < 8; hh++) {
        bf16x8 bfr = *(const bf16x8*)&QL[c * 264 + hh * 32 + quad * 8];
        #pragma unroll
        for (int i = 0; i < 4; i++) {
            int mt = w * 4 + i;
            bf16x8 afr = *(const bf16x8*)&WkB[(size_t)(mt * 16 + c) * 264 + hh * 32 + quad * 8];
            f32x4 d = MFMA16(afr, bfr, zero);
            if (c < 8) {
                int bb = b0 + (c >> 1);
                int qh = (c & 1) * 8 + hh;
                uint2 pk; pk.x = pack2(d[0], d[1]); pk.y = pack2(d[2], d[3]);
                *(uint2*)&U[((size_t)(bb * 16 + qh)) * 256 + mt * 16 + quad * 4] = pk;
            }
        }
    }
}

// ---------------------------------------------------------------------------
// K2 (hot, fused main+out): 256 blocks x 4 batches. 8 phases (4 batches x 2
// key-chunks): stream x (register prefetch), S = x@U per wave (wave-private
// softmax), PV accumulate in regs. Epilogue: Y (regs) -> LDS, per-head
// (Y@Wv+bv)*sp+tp -> zm, zm@Wo+bo -> out. Y never touches HBM.
// LDS ~77 KB -> 2 blocks/CU.
// ---------------------------------------------------------------------------
__global__ __launch_bounds__(256, 2) void k_mo(
    const float* __restrict__ node,
    const uint16_t* __restrict__ U,
    const float* __restrict__ ebhs,
    const uint16_t* __restrict__ WvT, const uint16_t* __restrict__ WoT,
    const float* __restrict__ bv, const float* __restrict__ bo,
    const float* __restrict__ sp, const float* __restrict__ tp,
    float* __restrict__ out)
{
    __shared__ uint16_t xc[64 * 264];     // 33.8 KB; reused as zm[8][264] in epilogue
    __shared__ uint16_t uL[64 * 264];     // 33.8 KB (U, 4 batches x 16 rows); reused as yL
    __shared__ uint16_t pL[4 * 16 * 72];  // 9.2 KB wave-private p
    __shared__ float ebhsL[64];
    const int b0 = blockIdx.x * 4;
    const int t = threadIdx.x, lane = t & 63, w = t >> 6, c = lane & 15, quad = lane >> 4;

    // stage U (4 batches x 16 rows x 256, contiguous) and ebhs
    #pragma unroll
    for (int i = 0; i < 8; i++) {
        int id = i * 256 + t;
        int row = id >> 5, c16 = id & 31;
        uint4 v = *(const uint4*)&U[((size_t)(b0 * 16) + row) * 256 + c16 * 8];
        *(uint4*)&uL[row * 264 + c16 * 8] = v;
    }
    if (t < 64) ebhsL[t] = ebhs[(size_t)b0 * 16 + t];

    float4 R[16];
    // load phase 0 (bi=0, ch=0)
    #pragma unroll
    for (int i = 0; i < 16; i++) {
        int f4 = i * 256 + t;
        int row = f4 >> 6, c4 = f4 & 63;
        R[i] = *(const float4*)(node + ((size_t)(b0)*128 + row) * 256 + c4 * 4);
    }
    // store phase 0 -> xc
    #pragma unroll
    for (int i = 0; i < 16; i++) {
        int f4 = i * 256 + t;
        int row = f4 >> 6, c4 = f4 & 63;
        uint2 pv; pv.x = pack2(R[i].x, R[i].y); pv.y = pack2(R[i].z, R[i].w);
        int col = (c4 * 4 + ((row >> 3) & 3) * 16) & 255;
        *(uint2*)&xc[row * 264 + col] = pv;
    }
    __syncthreads();

    const int q = c >> 3, h = c & 7;
    f32x4 zero = {0, 0, 0, 0};
    f32x4 yacc[4][4];
    #pragma unroll
    for (int bi = 0; bi < 4; bi++)
        #pragma unroll
        for (int tt = 0; tt < 4; tt++) yacc[bi][tt] = zero;
    float mrow[4] = {-1e30f, -1e30f, -1e30f, -1e30f};
    float lrow[4] = {0, 0, 0, 0};
    uint16_t* pW = &pL[w * 16 * 72];

    for (int p = 0; p < 8; p++) {
        const int bi = p >> 1, ch = p & 1;
        // prefetch next phase
        if (p < 7) {
            int nbi = (p + 1) >> 1, nch = (p + 1) & 1;
            #pragma unroll
            for (int i = 0; i < 16; i++) {
                int f4 = i * 256 + t;
                int row = f4 >> 6, c4 = f4 & 63;
                R[i] = *(const float4*)(node + ((size_t)(b0 + nbi) * 128 + nch * 64 + row) * 256 + c4 * 4);
            }
        }
        const float scaleF = 0.17677669529663687f * (1.0f + ebhsL[bi * 16 + 8 + h]);
        const float ebv = ebhsL[bi * 16 + h];
        // S: full 16x64 chunk per wave
        f32x4 sacc[4];
        #pragma unroll
        for (int kt = 0; kt < 4; kt++) sacc[kt] = zero;
        #pragma unroll
        for (int kk = 0; kk < 8; kk++) {
            bf16x8 bfr = *(const bf16x8*)&uL[(bi * 16 + c) * 264 + kk * 32 + quad * 8];
            #pragma unroll
            for (int kt = 0; kt < 4; kt++) {
                int arow = kt * 16 + c;
                int sh = ((arow >> 3) & 3) * 16;
                int colA = (kk * 32 + quad * 8 + sh) & 255;
                bf16x8 afr = *(const bf16x8*)&xc[arow * 264 + colA];
                sacc[kt] = MFMA16(afr, bfr, sacc[kt]);
            }
        }
        // softmax (wave-private; rows dup across quads)
        float v0[4][4];
        float lmax = -1e30f;
        #pragma unroll
        for (int kt = 0; kt < 4; kt++) {
            #pragma unroll
            for (int r = 0; r < 4; r++) {
                int krow = ch * 64 + kt * 16 + quad * 4 + r;
                float x = sacc[kt][r] * scaleF;
                if ((q == 0 && krow == 127) || (q == 1 && krow == 63)) x += ebv;
                v0[kt][r] = x;
                lmax = fmaxf(lmax, x);
            }
        }
        lmax = fmaxf(lmax, __shfl_xor(lmax, 16, 64));
        lmax = fmaxf(lmax, __shfl_xor(lmax, 32, 64));
        float mnew = fmaxf(mrow[bi], lmax);
        float alpha = __expf(mrow[bi] - mnew);
        float lsum = 0.0f;
        #pragma unroll
        for (int kt = 0; kt < 4; kt++) {
            float p0 = __expf(v0[kt][0] - mnew);
            float p1 = __expf(v0[kt][1] - mnew);
            float p2 = __expf(v0[kt][2] - mnew);
            float p3 = __expf(v0[kt][3] - mnew);
            lsum += (p0 + p1) + (p2 + p3);
            uint2 pk; pk.x = pack2(p0, p1); pk.y = pack2(p2, p3);
            *(uint2*)&pW[c * 72 + kt * 16 + quad * 4] = pk;
        }
        lsum += __shfl_xor(lsum, 16, 64);
        lsum += __shfl_xor(lsum, 32, 64);
        lrow[bi] = lrow[bi] * alpha + lsum;
        mrow[bi] = mnew;
        #pragma unroll
        for (int r = 0; r < 4; r++) {
            float aj = __shfl(alpha, quad * 4 + r, 64);
            #pragma unroll
            for (int tt = 0; tt < 4; tt++) yacc[bi][tt][r] *= aj;
        }
        // PV
        #pragma unroll
        for (int kk = 0; kk < 2; kk++) {
            bf16x8 afr = *(const bf16x8*)&pW[c * 72 + kk * 32 + quad * 8];
            int kbase = kk * 32 + quad * 8;
            int sh = ((kbase >> 3) & 3) * 16;
            #pragma unroll
            for (int tt = 0; tt < 4; tt++) {
                int n = w * 64 + tt * 16 + c;
                int col = (n + sh) & 255;
                union { bf16x8 v; uint32_t u[4]; } bb;
                #pragma unroll
                for (int jj = 0; jj < 4; jj++) {
                    uint32_t lo = xc[(kbase + 2 * jj) * 264 + col];
                    uint32_t hi = xc[(kbase + 2 * jj + 1) * 264 + col];
                    bb.u[jj] = lo | (hi << 16);
                }
                yacc[bi][tt] = MFMA16(afr, bb.v, yacc[bi][tt]);
            }
        }
        if (p < 7) {
            __syncthreads(); // all waves done reading xc(p)
            #pragma unroll
            for (int i = 0; i < 16; i++) {
                int f4 = i * 256 + t;
                int row = f4 >> 6, c4 = f4 & 63;
                uint2 pv; pv.x = pack2(R[i].x, R[i].y); pv.y = pack2(R[i].z, R[i].w);
                int col = (c4 * 4 + ((row >> 3) & 3) * 16) & 255;
                *(uint2*)&xc[row * 264 + col] = pv;
            }
            __syncthreads(); // xc(p+1) ready
        }
    }

    // ---- epilogue: Y (regs) -> yL (reuse uL); per-head Wv GEMM; Wo GEMM ----
    __syncthreads(); // everyone done with uL (S) and xc (PV)
    uint16_t* yL = uL;
    #pragma unroll
    for (int bi = 0; bi < 4; bi++) {
        float invr = 1.0f / lrow[bi];
        #pragma unroll
        for (int r = 0; r < 4; r++) {
            float invj = __shfl(invr, quad * 4 + r, 64);
            #pragma unroll
            for (int tt = 0; tt < 4; tt++) {
                int n = w * 64 + tt * 16 + c;
                yL[(bi * 16 + quad * 4 + r) * 264 + n] = f2bf(yacc[bi][tt][r] * invj);
            }
        }
    }
    __syncthreads(); // yL complete
    uint16_t* zm = xc; // rows 0..7 = (bi*2+q), cols 256
    #pragma unroll
    for (int hi = 0; hi < 2; hi++) {
        int hh = w * 2 + hi;
        f32x4 zacc[2];
        zacc[0] = zero; zacc[1] = zero;
        int mr = c & 7;
        int yrow = (mr >> 1) * 16 + (mr & 1) * 8 + hh;
        #pragma unroll
        for (int kk = 0; kk < 8; kk++) {
            bf16x8 afr = *(const bf16x8*)&yL[yrow * 264 + kk * 32 + quad * 8];
            #pragma unroll
            for (int nt = 0; nt < 2; nt++) {
                bf16x8 bfr = *(const bf16x8*)&WvT[(size_t)(hh * 32 + nt * 16 + c) * 264 + kk * 32 + quad * 8];
                zacc[nt] = MFMA16(afr, bfr, zacc[nt]);
            }
        }
        #pragma unroll
        for (int nt = 0; nt < 2; nt++) {
            int col = hh * 32 + nt * 16 + c;
            float bvv = bv[col];
            #pragma unroll
            for (int r = 0; r < 4; r++) {
                int m = quad * 4 + r;
                if (m < 8) {
                    int bb = b0 + (m >> 1);
                    float z = zacc[nt][r] + bvv;
                    zm[m * 264 + col] = f2bf(z * sp[(size_t)bb * 256 + col] + tp[(size_t)bb * 256 + col]);
                }
            }
        }
    }
    __syncthreads(); // zm complete
    #pragma unroll
    for (int i = 0; i < 4; i++) {
        int n = (w * 4 + i) * 16 + c;
        f32x4 fa = zero;
        #pragma unroll
        for (int kk = 0; kk < 8; kk++) {
            bf16x8 afr = *(const bf16x8*)&zm[(c & 7) * 264 + kk * 32 + quad * 8];
            bf16x8 bfr = *(const bf16x8*)&WoT[(size_t)n * 264 + kk * 32 + quad * 8];
            fa = MFMA16(afr, bfr, fa);
        }
        float bov = bo[n];
        #pragma unroll
        for (int r = 0; r < 4; r++) {
            int m = quad * 4 + r;
            if (m < 8) out[(size_t)(b0 * 2 + m) * 256 + n] = fa[r] + bov;
        }
    }
}

// ---------------------------------------------------------------------------
extern "C" void kernel_launch(void* const* d_in, const int* in_sizes, int n_in,
                              void* d_out, int out_size, void* d_ws, size_t ws_size,
                              hipStream_t stream) {
    const float* node   = (const float*)d_in[0];
    const float* edge   = (const float*)d_in[1];
    const float* Wq     = (const float*)d_in[2];
    const float* bq     = (const float*)d_in[3];
    const float* Wk     = (const float*)d_in[4];
    // d_in[5] = bk : provably unused (softmax-shift invariant)
    const float* Wv     = (const float*)d_in[6];
    const float* bv     = (const float*)d_in[7];
    const float* Wo     = (const float*)d_in[8];
    const float* bo     = (const float*)d_in[9];
    const float* Wbias  = (const float*)d_in[10];
    const float* bbias  = (const float*)d_in[11];
    const float* Wgate  = (const float*)d_in[12];
    const float* bgate  = (const float*)d_in[13];
    const float* Wscale = (const float*)d_in[14];
    const float* bscale = (const float*)d_in[15];
    const float* Wshift = (const float*)d_in[16];
    const float* bshift = (const float*)d_in[17];
    const float* Whead  = (const float*)d_in[18];
    const float* bhead  = (const float*)d_in[19];

    char* ws = (char*)d_ws;
    uint16_t* WqT  = (uint16_t*)(ws + 0);
    uint16_t* WvT  = (uint16_t*)(ws + 135168);
    uint16_t* WoT  = (uint16_t*)(ws + 270336);
    uint16_t* WkB  = (uint16_t*)(ws + 405504);
    float*    spw  = (float*)(ws + 540672);
    float*    tpw  = (float*)(ws + 1589248);
    float*    ebhs = (float*)(ws + 2637824);
    uint16_t* Uw   = (uint16_t*)(ws + 2703360);

    k_wt<<<dim3(4, 4, 4), 256, 0, stream>>>(Wq, Wv, Wo, Wk, WqT, WvT, WoT, WkB);
    k_eq<<<512, 256, 0, stream>>>(edge, Wgate, bgate, Wscale, bscale, Wshift, bshift,
                                  Wbias, bbias, Whead, bhead, spw, tpw, ebhs,
                                  node, WqT, WkB, bq, Uw);
    k_mo<<<256, 256, 0, stream>>>(node, Uw, ebhs, WvT, WoT, bv, bo, spw, tpw,
                                  (float*)d_out);
}

// Round 6
// 279.522 us; speedup vs baseline: 1.1059x; 1.1059x over previous
//
#include <hip/hip_runtime.h>
#include <cstdint>
#include <cstddef>

// Shapes (fixed): B=1024, N=2, HIST=64, D=256, E=128, NH=8, HD=32, s=128
// queries kept: s=63 (q=0), s=127 (q=1)

typedef short bf16x8 __attribute__((ext_vector_type(8)));
typedef float f32x4 __attribute__((ext_vector_type(4)));

#define MFMA16(A, B, C) __builtin_amdgcn_mfma_f32_16x16x32_bf16((A), (B), (C), 0, 0, 0)

static __device__ __forceinline__ uint16_t f2bf(float f) {
    uint32_t u = __builtin_bit_cast(uint32_t, f);
    u += 0x7FFFu + ((u >> 16) & 1u);
    return (uint16_t)(u >> 16);
}
static __device__ __forceinline__ uint32_t pack2(float a, float b) {
    return (uint32_t)f2bf(a) | ((uint32_t)f2bf(b) << 16);
}

// ---------------------------------------------------------------------------
// K0: z<3: transpose Wq/Wv/Wo (fp32 [k][n]) -> bf16 [n][264]
//     z==3: straight-convert Wk -> bf16 [j][264].
// ---------------------------------------------------------------------------
__global__ __launch_bounds__(256) void k_wt(
    const float* __restrict__ Wq, const float* __restrict__ Wv,
    const float* __restrict__ Wo, const float* __restrict__ Wk,
    uint16_t* __restrict__ WqT, uint16_t* __restrict__ WvT,
    uint16_t* __restrict__ WoT, uint16_t* __restrict__ WkB)
{
    const int t = threadIdx.x;
    const int tr = blockIdx.x, tc = blockIdx.y, z = blockIdx.z;
    if (z == 3) {
        #pragma unroll
        for (int i = 0; i < 16; i++) {
            int flat = i * 256 + t;
            int lr = flat >> 6, lc = flat & 63;
            WkB[(size_t)(tr * 64 + lr) * 264 + tc * 64 + lc] =
                f2bf(Wk[(size_t)(tr * 64 + lr) * 256 + tc * 64 + lc]);
        }
        return;
    }
    const float* W = (z == 0) ? Wq : ((z == 1) ? Wv : Wo);
    uint16_t* O = (z == 0) ? WqT : ((z == 1) ? WvT : WoT);
    __shared__ float tile[64][65];
    #pragma unroll
    for (int i = 0; i < 16; i++) {
        int flat = i * 256 + t;
        int lr = flat >> 6, lc = flat & 63;
        tile[lr][lc] = W[(size_t)(tr * 64 + lr) * 256 + tc * 64 + lc];
    }
    __syncthreads();
    #pragma unroll
    for (int i = 0; i < 16; i++) {
        int flat = i * 256 + t;
        int orow = flat >> 6, oc = flat & 63;
        O[(size_t)(tc * 64 + orow) * 264 + tr * 64 + oc] = f2bf(tile[oc][orow]);
    }
}

// ---------------------------------------------------------------------------
// K1 (parallel roles): blocks [0,256): edge modulations (4 batches);
// blocks [256,512): Q/U computation (4 batches each).
// ---------------------------------------------------------------------------
__global__ __launch_bounds__(256) void k_eq(
    const float* __restrict__ edge,
    const float* __restrict__ Wgate, const float* __restrict__ bgate,
    const float* __restrict__ Wscale, const float* __restrict__ bscale,
    const float* __restrict__ Wshift, const float* __restrict__ bshift,
    const float* __restrict__ Wbias, const float* __restrict__ bbias,
    const float* __restrict__ Whead, const float* __restrict__ bhead,
    float* __restrict__ sp, float* __restrict__ tp, float* __restrict__ ebhs,
    const float* __restrict__ node, const uint16_t* __restrict__ WqT,
    const uint16_t* __restrict__ WkB, const float* __restrict__ bq,
    uint16_t* __restrict__ U)
{
    __shared__ char smem[2 * 16 * 264 * 2];
    const int t = threadIdx.x;
    if (blockIdx.x < 256) {
        float* eL = (float*)smem; // [4][128]
        const int b0 = blockIdx.x * 4;
        for (int idx = t; idx < 512; idx += 256) {
            int bi = idx >> 7, e = idx & 127;
            eL[bi * 128 + e] = edge[(size_t)(b0 + bi) * 128 + e];
        }
        __syncthreads();
        float ag[4] = {0, 0, 0, 0}, asr[4] = {0, 0, 0, 0}, ah[4] = {0, 0, 0, 0};
        for (int e = 0; e < 128; e++) {
            float wg = Wgate[e * 256 + t];
            float wsc = Wscale[e * 256 + t];
            float wsh = Wshift[e * 256 + t];
            #pragma unroll
            for (int bi = 0; bi < 4; bi++) {
                float xv = eL[bi * 128 + e];
                ag[bi] = fmaf(xv, wg, ag[bi]);
                asr[bi] = fmaf(xv, wsc, asr[bi]);
                ah[bi] = fmaf(xv, wsh, ah[bi]);
            }
        }
        float bg = bgate[t], bs = bscale[t], bsh = bshift[t];
        #pragma unroll
        for (int bi = 0; bi < 4; bi++) {
            float g = 1.0f / (1.0f + __expf(-(ag[bi] + bg)));
            float sc = tanhf(asr[bi] + bs);
            float sh = ah[bi] + bsh;
            sp[(size_t)(b0 + bi) * 256 + t] = (1.0f + sc) * g;
            tp[(size_t)(b0 + bi) * 256 + t] = sh * g;
        }
        if (t < 64) {
            int bi = t >> 4, o = t & 15, h = o & 7;
            const float* W = (o < 8) ? Wbias : Whead;
            float a = 0.0f;
            for (int e = 0; e < 128; e++) a = fmaf(eL[bi * 128 + e], W[e * 8 + h], a);
            float val = (o < 8) ? (a + bbias[h]) : tanhf(a + bhead[h]);
            ebhs[(size_t)(b0 + bi) * 16 + o] = val;
        }
        return;
    }
    // ---- qu path ----
    uint16_t* xq = (uint16_t*)smem;
    uint16_t* QL = (uint16_t*)smem + 16 * 264;
    const int lane = t & 63, w = t >> 6, c = lane & 15, quad = lane >> 4;
    const int b0 = (blockIdx.x - 256) * 4;
    #pragma unroll
    for (int i = 0; i < 4; i++) {
        int flat4 = i * 256 + t;
        int row = flat4 >> 6, c4 = flat4 & 63;
        int r = row & 7;
        int bb = b0 + (r >> 1);
        int s = (r & 1) ? 127 : 63;
        const float4 v = *(const float4*)(node + ((size_t)(bb * 128 + s)) * 256 + c4 * 4);
        uint2 pv; pv.x = pack2(v.x, v.y); pv.y = pack2(v.z, v.w);
        *(uint2*)&xq[row * 264 + c4 * 4] = pv;
    }
    __syncthreads();
    f32x4 zero = {0, 0, 0, 0};
    f32x4 acc[4];
    #pragma unroll
    for (int i = 0; i < 4; i++) acc[i] = zero;
    #pragma unroll
    for (int kk = 0; kk < 8; kk++) {
        bf16x8 afr = *(const bf16x8*)&xq[c * 264 + kk * 32 + quad * 8];
        #pragma unroll
        for (int i = 0; i < 4; i++) {
            int nt = w * 4 + i;
            bf16x8 bfr = *(const bf16x8*)&WqT[(size_t)(nt * 16 + c) * 264 + kk * 32 + quad * 8];
            acc[i] = MFMA16(afr, bfr, acc[i]);
        }
    }
    #pragma unroll
    for (int i = 0; i < 4; i++) {
        int nt = w * 4 + i;
        float bqv = bq[nt * 16 + c];
        #pragma unroll
        for (int r = 0; r < 4; r++) {
            QL[(quad * 4 + r) * 264 + nt * 16 + c] = f2bf(acc[i][r] + bqv);
        }
    }
    __syncthreads();
    for (int hh = 0; hh < 8; hh++) {
        bf16x8 bfr = *(const bf16x8*)&QL[c * 264 + hh * 32 + quad * 8];
        #pragma unroll
        for (int i = 0; i < 4; i++) {
            int mt = w * 4 + i;
            bf16x8 afr = *(const bf16x8*)&WkB[(size_t)(mt * 16 + c) * 264 + hh * 32 + quad * 8];
            f32x4 d = MFMA16(afr, bfr, zero);
            if (c < 8) {
                int bb = b0 + (c >> 1);
                int qh = (c & 1) * 8 + hh;
                uint2 pk; pk.x = pack2(d[0], d[1]); pk.y = pack2(d[2], d[3]);
                *(uint2*)&U[((size_t)(bb * 16 + qh)) * 256 + mt * 16 + quad * 4] = pk;
            }
        }
    }
}

// ---------------------------------------------------------------------------
// K2 (hot, fused main+out, 1024 blocks x 1 batch): stream x (2 chunks,
// register prefetch), wave-private online softmax, PV in regs; epilogue
// per batch: Y->LDS, (Y@Wv+bv)*sp+tp -> zm, zm@Wo+bo -> out. Y never
// touches HBM. LDS ~52 KB -> 3 blocks/CU (12 waves/CU).
// ---------------------------------------------------------------------------
__global__ __launch_bounds__(256, 3) void k_mo(
    const float* __restrict__ node,
    const uint16_t* __restrict__ U,
    const float* __restrict__ ebhs,
    const uint16_t* __restrict__ WvT, const uint16_t* __restrict__ WoT,
    const float* __restrict__ bv, const float* __restrict__ bo,
    const float* __restrict__ sp, const float* __restrict__ tp,
    float* __restrict__ out)
{
    __shared__ uint16_t xc[64 * 264];     // 33.8 KB; reused as zm in epilogue
    __shared__ uint16_t uL[16 * 264];     // 8.4 KB; reused as yL
    __shared__ uint16_t pL[4 * 16 * 72];  // 9.2 KB wave-private p
    __shared__ float ebhsL[16];
    const int b = blockIdx.x;
    const int t = threadIdx.x, lane = t & 63, w = t >> 6, c = lane & 15, quad = lane >> 4;

    #pragma unroll
    for (int i = 0; i < 2; i++) {
        int flat = i * 256 + t;
        int row = flat >> 5, c16 = flat & 31;
        uint4 v = *(const uint4*)&U[((size_t)b * 16 + row) * 256 + c16 * 8];
        *(uint4*)&uL[row * 264 + c16 * 8] = v;
    }
    if (t < 16) ebhsL[t] = ebhs[(size_t)b * 16 + t];

    float4 R[16];
    #pragma unroll
    for (int i = 0; i < 16; i++) {
        int f4 = i * 256 + t;
        int row = f4 >> 6, c4 = f4 & 63;
        R[i] = *(const float4*)(node + ((size_t)b * 128 + row) * 256 + c4 * 4);
    }
    #pragma unroll
    for (int i = 0; i < 16; i++) {
        int f4 = i * 256 + t;
        int row = f4 >> 6, c4 = f4 & 63;
        uint2 pv; pv.x = pack2(R[i].x, R[i].y); pv.y = pack2(R[i].z, R[i].w);
        int col = (c4 * 4 + ((row >> 3) & 3) * 16) & 255;
        *(uint2*)&xc[row * 264 + col] = pv;
    }
    __syncthreads();

    const int q = c >> 3, h = c & 7;
    const float scaleF = 0.17677669529663687f * (1.0f + ebhsL[8 + h]);
    const float ebv = ebhsL[h];
    f32x4 zero = {0, 0, 0, 0};
    f32x4 yacc[4];
    #pragma unroll
    for (int tt = 0; tt < 4; tt++) yacc[tt] = zero;
    float mrow = -1e30f, lrow = 0.0f;
    uint16_t* pW = &pL[w * 16 * 72];

    #pragma unroll
    for (int ch = 0; ch < 2; ch++) {
        if (ch == 0) {
            #pragma unroll
            for (int i = 0; i < 16; i++) {
                int f4 = i * 256 + t;
                int row = f4 >> 6, c4 = f4 & 63;
                R[i] = *(const float4*)(node + ((size_t)b * 128 + 64 + row) * 256 + c4 * 4);
            }
        }
        // S: full 16x64 chunk per wave
        f32x4 sacc[4];
        #pragma unroll
        for (int kt = 0; kt < 4; kt++) sacc[kt] = zero;
        #pragma unroll
        for (int kk = 0; kk < 8; kk++) {
            bf16x8 bfr = *(const bf16x8*)&uL[c * 264 + kk * 32 + quad * 8];
            #pragma unroll
            for (int kt = 0; kt < 4; kt++) {
                int arow = kt * 16 + c;
                int sh = ((arow >> 3) & 3) * 16;
                int colA = (kk * 32 + quad * 8 + sh) & 255;
                bf16x8 afr = *(const bf16x8*)&xc[arow * 264 + colA];
                sacc[kt] = MFMA16(afr, bfr, sacc[kt]);
            }
        }
        float v0[4][4];
        float lmax = -1e30f;
        #pragma unroll
        for (int kt = 0; kt < 4; kt++) {
            #pragma unroll
            for (int r = 0; r < 4; r++) {
                int krow = ch * 64 + kt * 16 + quad * 4 + r;
                float x = sacc[kt][r] * scaleF;
                if ((q == 0 && krow == 127) || (q == 1 && krow == 63)) x += ebv;
                v0[kt][r] = x;
                lmax = fmaxf(lmax, x);
            }
        }
        lmax = fmaxf(lmax, __shfl_xor(lmax, 16, 64));
        lmax = fmaxf(lmax, __shfl_xor(lmax, 32, 64));
        float mnew = fmaxf(mrow, lmax);
        float alpha = __expf(mrow - mnew);
        float lsum = 0.0f;
        #pragma unroll
        for (int kt = 0; kt < 4; kt++) {
            float p0 = __expf(v0[kt][0] - mnew);
            float p1 = __expf(v0[kt][1] - mnew);
            float p2 = __expf(v0[kt][2] - mnew);
            float p3 = __expf(v0[kt][3] - mnew);
            lsum += (p0 + p1) + (p2 + p3);
            uint2 pk; pk.x = pack2(p0, p1); pk.y = pack2(p2, p3);
            *(uint2*)&pW[c * 72 + kt * 16 + quad * 4] = pk;
        }
        lsum += __shfl_xor(lsum, 16, 64);
        lsum += __shfl_xor(lsum, 32, 64);
        lrow = lrow * alpha + lsum;
        mrow = mnew;
        #pragma unroll
        for (int r = 0; r < 4; r++) {
            float aj = __shfl(alpha, quad * 4 + r, 64);
            #pragma unroll
            for (int tt = 0; tt < 4; tt++) yacc[tt][r] *= aj;
        }
        // PV
        #pragma unroll
        for (int kk = 0; kk < 2; kk++) {
            bf16x8 afr = *(const bf16x8*)&pW[c * 72 + kk * 32 + quad * 8];
            int kbase = kk * 32 + quad * 8;
            int sh = ((kbase >> 3) & 3) * 16;
            #pragma unroll
            for (int tt = 0; tt < 4; tt++) {
                int n = w * 64 + tt * 16 + c;
                int col = (n + sh) & 255;
                union { bf16x8 v; uint32_t u[4]; } bb;
                #pragma unroll
                for (int jj = 0; jj < 4; jj++) {
                    uint32_t lo = xc[(kbase + 2 * jj) * 264 + col];
                    uint32_t hi = xc[(kbase + 2 * jj + 1) * 264 + col];
                    bb.u[jj] = lo | (hi << 16);
                }
                yacc[tt] = MFMA16(afr, bb.v, yacc[tt]);
            }
        }
        if (ch == 0) {
            __syncthreads();
            #pragma unroll
            for (int i = 0; i < 16; i++) {
                int f4 = i * 256 + t;
                int row = f4 >> 6, c4 = f4 & 63;
                uint2 pv; pv.x = pack2(R[i].x, R[i].y); pv.y = pack2(R[i].z, R[i].w);
                int col = (c4 * 4 + ((row >> 3) & 3) * 16) & 255;
                *(uint2*)&xc[row * 264 + col] = pv;
            }
            __syncthreads();
        }
    }

    // ---- epilogue ----
    __syncthreads(); // all waves done with uL (S) and xc (PV)
    uint16_t* yL = uL; // rows: qh = q*8+h, cols 0..255 (plain stride 264)
    {
        float invr = 1.0f / lrow;
        #pragma unroll
        for (int r = 0; r < 4; r++) {
            float invj = __shfl(invr, quad * 4 + r, 64);
            #pragma unroll
            for (int tt = 0; tt < 4; tt++) {
                int n = w * 64 + tt * 16 + c;
                yL[(quad * 4 + r) * 264 + n] = f2bf(yacc[tt][r] * invj);
            }
        }
    }
    __syncthreads();
    uint16_t* zm = xc; // rows 0..1 (= q), cols 256
    #pragma unroll
    for (int hi = 0; hi < 2; hi++) {
        int hh = w * 2 + hi;
        f32x4 zacc[2];
        zacc[0] = zero; zacc[1] = zero;
        int yrow = (c & 1) * 8 + hh; // A row m=c -> (q=m&1, head hh); dup x8
        #pragma unroll
        for (int kk = 0; kk < 8; kk++) {
            bf16x8 afr = *(const bf16x8*)&yL[yrow * 264 + kk * 32 + quad * 8];
            #pragma unroll
            for (int nt = 0; nt < 2; nt++) {
                bf16x8 bfr = *(const bf16x8*)&WvT[(size_t)(hh * 32 + nt * 16 + c) * 264 + kk * 32 + quad * 8];
                zacc[nt] = MFMA16(afr, bfr, zacc[nt]);
            }
        }
        #pragma unroll
        for (int nt = 0; nt < 2; nt++) {
            int col = hh * 32 + nt * 16 + c;
            float bvv = bv[col];
            #pragma unroll
            for (int r = 0; r < 4; r++) {
                int m = quad * 4 + r; // valid rows m<2 (q=m)
                if (m < 2) {
                    float z = zacc[nt][r] + bvv;
                    zm[m * 264 + col] = f2bf(z * sp[(size_t)b * 256 + col] + tp[(size_t)b * 256 + col]);
                }
            }
        }
    }
    __syncthreads();
    #pragma unroll
    for (int i = 0; i < 4; i++) {
        int n = (w * 4 + i) * 16 + c;
        f32x4 fa = zero;
        #pragma unroll
        for (int kk = 0; kk < 8; kk++) {
            bf16x8 afr = *(const bf16x8*)&zm[(c & 1) * 264 + kk * 32 + quad * 8];
            bf16x8 bfr = *(const bf16x8*)&WoT[(size_t)n * 264 + kk * 32 + quad * 8];
            fa = MFMA16(afr, bfr, fa);
        }
        float bov = bo[n];
        #pragma unroll
        for (int r = 0; r < 4; r++) {
            int m = quad * 4 + r;
            if (m < 2) out[(size_t)(b * 2 + m) * 256 + n] = fa[r] + bov;
        }
    }
}

// ---------------------------------------------------------------------------
extern "C" void kernel_launch(void* const* d_in, const int* in_sizes, int n_in,
                              void* d_out, int out_size, void* d_ws, size_t ws_size,
                              hipStream_t stream) {
    const float* node   = (const float*)d_in[0];
    const float* edge   = (const float*)d_in[1];
    const float* Wq     = (const float*)d_in[2];
    const float* bq     = (const float*)d_in[3];
    const float* Wk     = (const float*)d_in[4];
    // d_in[5] = bk : provably unused (softmax-shift invariant)
    const float* Wv     = (const float*)d_in[6];
    const float* bv     = (const float*)d_in[7];
    const float* Wo     = (const float*)d_in[8];
    const float* bo     = (const float*)d_in[9];
    const float* Wbias  = (const float*)d_in[10];
    const float* bbias  = (const float*)d_in[11];
    const float* Wgate  = (const float*)d_in[12];
    const float* bgate  = (const float*)d_in[13];
    const float* Wscale = (const float*)d_in[14];
    const float* bscale = (const float*)d_in[15];
    const float* Wshift = (const float*)d_in[16];
    const float* bshift = (const float*)d_in[17];
    const float* Whead  = (const float*)d_in[18];
    const float* bhead  = (const float*)d_in[19];

    char* ws = (char*)d_ws;
    uint16_t* WqT  = (uint16_t*)(ws + 0);
    uint16_t* WvT  = (uint16_t*)(ws + 135168);
    uint16_t* WoT  = (uint16_t*)(ws + 270336);
    uint16_t* WkB  = (uint16_t*)(ws + 405504);
    float*    spw  = (float*)(ws + 540672);
    float*    tpw  = (float*)(ws + 1589248);
    float*    ebhs = (float*)(ws + 2637824);
    uint16_t* Uw   = (uint16_t*)(ws + 2703360);

    k_wt<<<dim3(4, 4, 4), 256, 0, stream>>>(Wq, Wv, Wo, Wk, WqT, WvT, WoT, WkB);
    k_eq<<<512, 256, 0, stream>>>(edge, Wgate, bgate, Wscale, bscale, Wshift, bshift,
                                  Wbias, bbias, Whead, bhead, spw, tpw, ebhs,
                                  node, WqT, WkB, bq, Uw);
    k_mo<<<1024, 256, 0, stream>>>(node, Uw, ebhs, WvT, WoT, bv, bo, spw, tpw,
                                   (float*)d_out);
}